// Round 3
// baseline (350.630 us; speedup 1.0000x reference)
//
#include <hip/hip_runtime.h>
#include <math.h>

// SkipGram negative-sampling loss on MI355X — round 8.
// R6/R7 post-mortem: forcing a register-resident prefetch pipeline spilled
// both times (WRITE_SIZE 53MB/33MB) — regalloc will not fund 96 payload
// VGPRs across the butterfly. Pivot: get memory-level parallelism from
// WAVE COUNT instead of per-wave registers. One sample per wave:
//   12 scalar index loads -> burst of 24 row loads -> dot -> butterfly ->
//   softplus -> die. 65536 short waves, no forced liveness, no pipeline.
// This is the discriminating experiment between "latency/concurrency
// limited" (BW should jump to 4.5-6 TB/s) and "~3.4 TB/s random-gather
// fabric ceiling" (BW stays put despite occupancy 75%+ and zero spill).

#define DIM   300
#define B_TOT 65536
#define K_NEG 10
#define NROW  (K_NEG + 2)   // u, pos_v, 10 negs

constexpr int TPB    = 256;
constexpr int WPB    = TPB / 64;        // 4 waves per block
constexpr int BLOCKS = B_TOT / WPB;     // 16384 blocks, 1 sample per wave

typedef float vf4 __attribute__((ext_vector_type(4)));

__device__ __forceinline__ float dot4(vf4 a, vf4 b) {
    vf4 p = a * b;
    return p.x + p.y + p.z + p.w;
}

__device__ __forceinline__ vf4 ld_nt(const vf4* p) {
    return __builtin_nontemporal_load(p);
}

// Row = 75 float4 (1200 B). Lane i covers chunk i; lanes 0..10 also cover
// chunks 64..74 (masked lanes re-read chunk `lane`; contribution zeroed —
// same line as the c0 load -> L1 hit, no extra fabric traffic).
__global__ __launch_bounds__(TPB) void sg_main(
    const float* __restrict__ uw, const float* __restrict__ vw,
    const int* __restrict__ pos_u, const int* __restrict__ pos_v,
    const int* __restrict__ neg_v, float* __restrict__ block_sums)
{
    const int lane = threadIdx.x & 63;
    const int wib  = threadIdx.x >> 6;
    int gw = blockIdx.x * WPB + wib;
    gw = __builtin_amdgcn_readfirstlane(gw);     // wave-uniform sample id

    const bool c1ok = lane < (75 - 64);          // lanes 0..10
    const int  o2   = c1ok ? (64 + lane) : lane; // in-bounds fallback

    const int b = gw;                            // one sample per wave

    // Wave-uniform index fetch -> s_loads.
    int idx[NROW];
    idx[0] = __builtin_amdgcn_readfirstlane(pos_u[b]);
    idx[1] = __builtin_amdgcn_readfirstlane(pos_v[b]);
    #pragma unroll
    for (int k = 0; k < K_NEG; ++k)
        idx[2 + k] = __builtin_amdgcn_readfirstlane(neg_v[b * K_NEG + k]);

    // Burst all 24 row loads. Pair order (c0[j],c1[j]) so the first dot's
    // vmcnt wait clears after 4 returns; compiler sizes the in-flight
    // window to its register budget — no forced liveness, no spill.
    vf4 c0[NROW];
    vf4 c1[NROW];
    {
        const vf4* bu = (const vf4*)(uw + (size_t)idx[0] * DIM);
        c0[0] = ld_nt(bu + lane);                // u row: non-temporal
        c1[0] = ld_nt(bu + o2);
    }
    #pragma unroll
    for (int j = 1; j < NROW; ++j) {
        const vf4* bv = (const vf4*)(vw + (size_t)idx[j] * DIM);
        c0[j] = bv[lane];
        c1[j] = bv[o2];
    }

    float part[K_NEG + 1];
    #pragma unroll
    for (int j = 1; j < NROW; ++j) {
        float p = dot4(c0[j], c0[0]);
        float q = dot4(c1[j], c1[0]);
        part[j - 1] = p + (c1ok ? q : 0.f);
    }

    // Butterfly-reduce all 11 dots across the wave (result broadcast).
    #pragma unroll
    for (int s = 1; s < 64; s <<= 1) {
        #pragma unroll
        for (int j = 0; j < K_NEG + 1; ++j)
            part[j] += __shfl_xor(part[j], s, 64);
    }

    // pos: softplus(-score); neg: softplus(+score)
    float score = fminf(fmaxf(part[0], -10.f), 10.f);
    float loss = __logf(1.f + __expf(-score));
    #pragma unroll
    for (int k = 0; k < K_NEG; ++k) {
        float ns = fminf(fmaxf(part[k + 1], -10.f), 10.f);
        loss += __logf(1.f + __expf(ns));
    }

    __shared__ float red[WPB];
    if (lane == 0) red[wib] = loss;
    __syncthreads();
    if (threadIdx.x == 0)
        block_sums[blockIdx.x] = red[0] + red[1] + red[2] + red[3];
}

__global__ __launch_bounds__(256) void sg_finalize(
    const float* __restrict__ bs, float* __restrict__ out)
{
    float s = 0.f;
    for (int i = threadIdx.x; i < BLOCKS; i += 256) s += bs[i];
    #pragma unroll
    for (int off = 1; off < 64; off <<= 1) s += __shfl_xor(s, off, 64);
    __shared__ float red[4];
    const int wave = threadIdx.x >> 6;
    if ((threadIdx.x & 63) == 0) red[wave] = s;
    __syncthreads();
    if (threadIdx.x == 0)
        out[0] = (red[0] + red[1] + red[2] + red[3]) * (1.0f / (float)B_TOT);
}

extern "C" void kernel_launch(void* const* d_in, const int* in_sizes, int n_in,
                              void* d_out, int out_size, void* d_ws, size_t ws_size,
                              hipStream_t stream) {
    const float* uw    = (const float*)d_in[0];
    const float* vw    = (const float*)d_in[1];
    const int*   pos_u = (const int*)d_in[2];
    const int*   pos_v = (const int*)d_in[3];
    const int*   neg_v = (const int*)d_in[4];
    float* out = (float*)d_out;
    float* block_sums = (float*)d_ws;   // 16384 floats = 64 KB

    sg_main<<<BLOCKS, TPB, 0, stream>>>(uw, vw, pos_u, pos_v, neg_v, block_sums);
    sg_finalize<<<1, 256, 0, stream>>>(block_sums, out);
}